// Round 2
// baseline (423.691 us; speedup 1.0000x reference)
//
#include <hip/hip_runtime.h>

typedef __bf16 bf16x8 __attribute__((ext_vector_type(8)));
typedef unsigned short u16x8 __attribute__((ext_vector_type(8)));
typedef float f32x4 __attribute__((ext_vector_type(4)));
typedef float f32x16 __attribute__((ext_vector_type(16)));

__device__ __forceinline__ unsigned short f2bf(float f) {
    unsigned u = __builtin_bit_cast(unsigned, f);
    u += 0x7FFFu + ((u >> 16) & 1u);            // RNE
    return (unsigned short)(u >> 16);
}

// ---------------------------------------------------------------------------
// Pre-kernel: build B = [Wa; Wb], col-major bf16 wt[i][kappa], kappa in [0,768):
//   kappa < 384 : w1[i,0] * w2[j2,k,i]   (kappa = k*128 + j2, tap-major)
//   kappa >= 384: w1[i,1] * w2[j2,k,i]
// ---------------------------------------------------------------------------
__global__ void prep_w(const float* __restrict__ w1, const float* __restrict__ w2,
                       unsigned short* __restrict__ wt) {
    int idx = blockIdx.x * 256 + threadIdx.x;       // flat over w2 (128,3,256)
    if (idx < 128 * 3 * 256) {
        int i  = idx & 255;
        int jk = idx >> 8;                          // j2*3 + k
        int j2 = jk / 3, k = jk - 3 * j2;
        float v = w2[idx];
        wt[(size_t)i * 768 + k * 128 + j2]       = f2bf(w1[2 * i] * v);
        wt[(size_t)i * 768 + 384 + k * 128 + j2] = f2bf(w1[2 * i + 1] * v);
    }
}

// ---------------------------------------------------------------------------
// Main kernel: one block per m. GEMM: out[196x256] = Awin[196x768] * B[768x256]
// where Awin rows are permuted/windowed views of the staged x rows (no epilogue).
// 32x32x16 bf16 MFMA, each wave: 2 n-tiles (64 cols) x 7 m-tiles, K=768.
// ---------------------------------------------------------------------------

#define XSTRIDE 136   // u16 per xlds row: 272 B, 16B-aligned
#define CBSTR   36    // f32 per cb col: 144 B, 16B-aligned

template<int NM>
__device__ __forceinline__ void gemm_group(
    int mt0, const unsigned short* xl, const unsigned short* wt,
    float* cbw, float* outm, int wave, int lane)
{
    const int l32 = lane & 31, half = lane >> 5;
    const int c0 = wave * 64 + l32;

    // per-(mt, phase, tap) A row base addresses (u16 units), zero-row = 196
    int rb1[NM][3], rb2[NM][3];
#pragma unroll
    for (int mi = 0; mi < NM; ++mi) {
        int e  = (mt0 + mi) * 32 + l32;
        int ec = e < 196 ? e : 195;                 // pad rows: garbage, masked at store
        int cdx = ec / 14;
        int n   = ec - 14 * cdx;
        int lA = (cdx + 13) % 14;                   // roll by 1
        int lB = (cdx + 12) % 14;                   // roll by 2
#pragma unroll
        for (int t = 0; t < 3; ++t) {
            bool valid = (t == 1) || ((t == 0) ? (n >= 1) : (n <= 12));
            int rA = valid ? (lA * 14 + n + t - 1) : 196;
            int rB = valid ? (lB * 14 + n + t - 1) : 196;
            rb1[mi][t] = rA * XSTRIDE + half * 8;
            rb2[mi][t] = rB * XSTRIDE + half * 8;
        }
    }

    f32x16 acc[NM][2];
#pragma unroll
    for (int mi = 0; mi < NM; ++mi)
#pragma unroll
        for (int nt = 0; nt < 2; ++nt)
#pragma unroll
            for (int q = 0; q < 16; ++q) acc[mi][nt][q] = 0.f;

    const unsigned short* wb0 = wt + (size_t)c0 * 768 + half * 8;

#pragma unroll 1
    for (int ph = 0; ph < 2; ++ph) {
        int rbp[NM][3];
#pragma unroll
        for (int mi = 0; mi < NM; ++mi)
#pragma unroll
            for (int t = 0; t < 3; ++t)
                rbp[mi][t] = (ph == 0) ? rb1[mi][t] : rb2[mi][t];
        const unsigned short* wb = wb0 + ph * 384;
#pragma unroll
        for (int tap = 0; tap < 3; ++tap) {
#pragma unroll
            for (int ss = 0; ss < 8; ++ss) {
                const int ko = tap * 128 + ss * 16;
                u16x8 b0 = *(const u16x8*)(wb + ko);
                u16x8 b1 = *(const u16x8*)(wb + 32 * 768 + ko);
#pragma unroll
                for (int mi = 0; mi < NM; ++mi) {
                    u16x8 av = *(const u16x8*)(xl + rbp[mi][tap] + ss * 16);
                    acc[mi][0] = __builtin_amdgcn_mfma_f32_32x32x16_bf16(
                        __builtin_bit_cast(bf16x8, av), __builtin_bit_cast(bf16x8, b0),
                        acc[mi][0], 0, 0, 0);
                    acc[mi][1] = __builtin_amdgcn_mfma_f32_32x32x16_bf16(
                        __builtin_bit_cast(bf16x8, av), __builtin_bit_cast(bf16x8, b1),
                        acc[mi][1], 0, 0, 0);
                }
            }
        }
    }

    // ---- store: 32x32 fp32 transpose through per-wave LDS, coalesced dwordx4 ----
    const int ib = lane >> 3;                       // 0..7  (col sub-index)
    const int eo = (lane & 7) * 4;                  // 0..28 (row = output e offset)
#pragma unroll
    for (int mi = 0; mi < NM; ++mi) {
        const int mt = mt0 + mi;
#pragma unroll
        for (int nt = 0; nt < 2; ++nt) {
            // C/D layout (verified): col = lane&31, row = (reg&3) + 8*(reg>>2) + 4*half
#pragma unroll
            for (int q = 0; q < 4; ++q) {
                f32x4 v = { acc[mi][nt][q * 4 + 0], acc[mi][nt][q * 4 + 1],
                            acc[mi][nt][q * 4 + 2], acc[mi][nt][q * 4 + 3] };
                *(f32x4*)&cbw[l32 * CBSTR + q * 8 + half * 4] = v;
            }
            asm volatile("s_waitcnt lgkmcnt(0)" ::: "memory");
#pragma unroll
            for (int r = 0; r < 4; ++r) {
                f32x4 v = *(const f32x4*)&cbw[(r * 8 + ib) * CBSTR + eo];
                if (mt < 6 || eo == 0) {            // e=192..195 is the only valid mt==6 chunk
                    float* op = outm + (size_t)(wave * 64 + nt * 32 + r * 8 + ib) * 196
                                     + mt * 32 + eo;
                    *(f32x4*)op = v;
                }
            }
            asm volatile("s_waitcnt lgkmcnt(0)" ::: "memory");  // reads done before next overwrite
        }
    }
}

__global__ __launch_bounds__(256, 2) void fused_conv_outer2(
    const float* __restrict__ x, const unsigned short* __restrict__ wt,
    float* __restrict__ out)
{
    __shared__ alignas(16) unsigned short xlds[197 * XSTRIDE];  // row 196 = zero row
    __shared__ alignas(16) float cb[4][32 * CBSTR];

    const int m    = blockIdx.x;
    const int tid  = threadIdx.x;
    const int wave = tid >> 6;
    const int lane = tid & 63;

    // ---------------- stage x4[m] -> xlds (bf16, transposed) ----------------
    {
        const float* xm = x + (size_t)m * 25088;    // x4[m][j2][l*14+h], j2 stride 196
        const int j2a = 2 * lane;                   // each lane owns 2 consecutive j2
        const int rbase = wave * 48;
        const int rend  = (wave == 3) ? 52 : 48;
        for (int rr = 0; rr < rend; rr += 4) {
            const float4 v0 = *(const float4*)(xm + (size_t)j2a * 196 + rbase + rr);
            const float4 v1 = *(const float4*)(xm + (size_t)(j2a + 1) * 196 + rbase + rr);
            const float a0[4] = {v0.x, v0.y, v0.z, v0.w};
            const float a1[4] = {v1.x, v1.y, v1.z, v1.w};
#pragma unroll
            for (int i2 = 0; i2 < 4; ++i2) {
                unsigned pk = (unsigned)f2bf(a0[i2]) | ((unsigned)f2bf(a1[i2]) << 16);
                *(unsigned*)&xlds[(rbase + rr + i2) * XSTRIDE + j2a] = pk;
            }
        }
        if (tid < XSTRIDE / 2)                       // zero row 196 (window padding)
            ((unsigned*)&xlds[196 * XSTRIDE])[tid] = 0u;
    }
    __syncthreads();

    float* outm = out + (size_t)m * 50176;
    gemm_group<4>(0, xlds, wt, cb[wave], outm, wave, lane);   // rows   0..127
    gemm_group<3>(4, xlds, wt, cb[wave], outm, wave, lane);   // rows 128..223 (196..223 masked)
}

extern "C" void kernel_launch(void* const* d_in, const int* in_sizes, int n_in,
                              void* d_out, int out_size, void* d_ws, size_t ws_size,
                              hipStream_t stream) {
    const float* x  = (const float*)d_in[0];        // (1024,1792,14) fp32
    const float* w1 = (const float*)d_in[1];        // (256,2) fp32
    const float* w2 = (const float*)d_in[2];        // (128,3,256) fp32
    float* out = (float*)d_out;                     // (1024,256,14,14) fp32
    unsigned short* wt = (unsigned short*)d_ws;     // 256*768 bf16 = 393,216 B

    prep_w<<<384, 256, 0, stream>>>(w1, w2, wt);
    fused_conv_outer2<<<1024, 256, 0, stream>>>(x, wt, out);
}